// Round 15
// baseline (35.197 us; speedup 1.0000x reference)
//
#include <hip/hip_runtime.h>
#include <hip/hip_bf16.h>
#include <stdint.h>

typedef unsigned long long u64;

#define S 16            // slices per row
#define SEGCAP 256      // per-slice candidate segment (expect ~182, 5.5-sigma safe)
#define NBF 8192        // fine bins for counting sort (range [2,8))
#define KBASE 0xC0000000u   // fkey(2.0f)
#define FSHIFT 11
#define KSHIFT 19       // coarse 13-bit key (slow path)
#define CAND_MAX 4096   // = S * SEGCAP
#define NT1 256
#define NW1 (NT1 / 64)
#define NTF 1024
#define NWF (NTF / 64)

__device__ __forceinline__ unsigned fkey(float x) {
    unsigned u = __float_as_uint(x);
    return ((int)u < 0) ? ~u : (u | 0x80000000u);
}

// ---------------- K1: single sweep: max + raw exp-sum + speculative collect ----
// 4-wide unrolled (4 independent loads in flight), 4 accumulator chains,
// native exp. Writes per-slice: gmax, gsum, gcnt16, gcand segment
// (sentinel-0 padded) -> no pre-zeroing anywhere.
__global__ __launch_bounds__(NT1) void k_pass1(
    const float* __restrict__ logits, const float* __restrict__ temps,
    float* __restrict__ gmax, float* __restrict__ gsum,
    u64* __restrict__ gcand, unsigned* __restrict__ gcnt16, int V, int slen)
{
    const int s = blockIdx.x, b = blockIdx.y, tid = threadIdx.x;
    __shared__ u64 buf[SEGCAP];
    __shared__ float redm[NW1], reds[NW1];
    __shared__ unsigned s_cnt;
    if (tid == 0) s_cnt = 0u;
    __syncthreads();

    const float t = temps[b];
    const float invt = 1.0f / t;      // denom-only rounding class (accepted)
    const float* xrow = logits + (size_t)b * (size_t)V;
    const int beg = s * slen, end = min(V, beg + slen);
    const float4* x4 = (const float4*)xrow;
    const int beg4 = beg >> 2, end4 = end >> 2;

    float lmax0 = -INFINITY, lmax1 = -INFINITY, lmax2 = -INFINITY, lmax3 = -INFINITY;
    float lsum0 = 0.f, lsum1 = 0.f, lsum2 = 0.f, lsum3 = 0.f;
    const float4 pad = make_float4(-INFINITY, -INFINITY, -INFINITY, -INFINITY);

#define COLLECT4(vv, ibase)                                                                                        \
    if (vv.x >= 2.0f) { unsigned p = atomicAdd(&s_cnt, 1u); if (p < SEGCAP) buf[p] = ((u64)__float_as_uint(vv.x) << 32) | (unsigned)((ibase)    ); } \
    if (vv.y >= 2.0f) { unsigned p = atomicAdd(&s_cnt, 1u); if (p < SEGCAP) buf[p] = ((u64)__float_as_uint(vv.y) << 32) | (unsigned)((ibase) + 1); } \
    if (vv.z >= 2.0f) { unsigned p = atomicAdd(&s_cnt, 1u); if (p < SEGCAP) buf[p] = ((u64)__float_as_uint(vv.z) << 32) | (unsigned)((ibase) + 2); } \
    if (vv.w >= 2.0f) { unsigned p = atomicAdd(&s_cnt, 1u); if (p < SEGCAP) buf[p] = ((u64)__float_as_uint(vv.w) << 32) | (unsigned)((ibase) + 3); }

    for (int idx = beg4 + tid; idx < end4; idx += 4 * NT1) {
        const int j1 = idx + NT1, j2 = idx + 2 * NT1, j3 = idx + 3 * NT1;
        float4 a0 = x4[idx];
        float4 a1 = (j1 < end4) ? x4[j1] : pad;   // __expf(-inf)=0, fmax neutral
        float4 a2 = (j2 < end4) ? x4[j2] : pad;
        float4 a3 = (j3 < end4) ? x4[j3] : pad;

        lmax0 = fmaxf(lmax0, fmaxf(fmaxf(a0.x, a0.y), fmaxf(a0.z, a0.w)));
        lmax1 = fmaxf(lmax1, fmaxf(fmaxf(a1.x, a1.y), fmaxf(a1.z, a1.w)));
        lmax2 = fmaxf(lmax2, fmaxf(fmaxf(a2.x, a2.y), fmaxf(a2.z, a2.w)));
        lmax3 = fmaxf(lmax3, fmaxf(fmaxf(a3.x, a3.y), fmaxf(a3.z, a3.w)));

        lsum0 += __expf(a0.x * invt); lsum0 += __expf(a0.y * invt);
        lsum0 += __expf(a0.z * invt); lsum0 += __expf(a0.w * invt);
        lsum1 += __expf(a1.x * invt); lsum1 += __expf(a1.y * invt);
        lsum1 += __expf(a1.z * invt); lsum1 += __expf(a1.w * invt);
        lsum2 += __expf(a2.x * invt); lsum2 += __expf(a2.y * invt);
        lsum2 += __expf(a2.z * invt); lsum2 += __expf(a2.w * invt);
        lsum3 += __expf(a3.x * invt); lsum3 += __expf(a3.y * invt);
        lsum3 += __expf(a3.z * invt); lsum3 += __expf(a3.w * invt);

        COLLECT4(a0, idx << 2);
        COLLECT4(a1, j1 << 2);
        COLLECT4(a2, j2 << 2);
        COLLECT4(a3, j3 << 2);
    }
#undef COLLECT4
    for (int i = max(beg, end4 << 2) + tid; i < end; i += NT1) {
        float x = xrow[i];
        lmax0 = fmaxf(lmax0, x);
        lsum0 += __expf(x * invt);
        if (x >= 2.0f) { unsigned p = atomicAdd(&s_cnt, 1u); if (p < SEGCAP) buf[p] = ((u64)__float_as_uint(x) << 32) | (unsigned)i; }
    }

    float lmax = fmaxf(fmaxf(lmax0, lmax1), fmaxf(lmax2, lmax3));
    float lsum = (lsum0 + lsum1) + (lsum2 + lsum3);
    for (int off = 32; off > 0; off >>= 1) {
        lmax = fmaxf(lmax, __shfl_xor(lmax, off));
        lsum += __shfl_xor(lsum, off);
    }
    if ((tid & 63) == 0) { redm[tid >> 6] = lmax; reds[tid >> 6] = lsum; }
    __syncthreads();
    if (tid == 0) {
        float m = redm[0], sum = reds[0];
        for (int w = 1; w < NW1; ++w) { m = fmaxf(m, redm[w]); sum += reds[w]; }
        gmax[b * S + s] = m;
        gsum[b * S + s] = sum;            // raw sum of exp(x/t), no max shift
        gcnt16[b * S + s] = s_cnt;        // raw count (> SEGCAP -> slow path)
    }
    __syncthreads();
    const unsigned cw = min(s_cnt, (unsigned)SEGCAP);
    u64* dst = gcand + (size_t)b * CAND_MAX + (size_t)s * SEGCAP;
    for (int i = tid; i < SEGCAP; i += NT1)
        dst[i] = (i < (int)cw) ? buf[i] : 0ULL;   // sentinel-pad the tail
}

// ---------------- K2: per-row finish: counting sort (fast) / rescan+bitonic (slow) ----
__global__ __launch_bounds__(NTF) void k_finish(
    const float* __restrict__ logits, const u64* __restrict__ gcand,
    const unsigned* __restrict__ gcnt16,
    const float* __restrict__ gmax, const float* __restrict__ gsum,
    const float* __restrict__ temps, const float* __restrict__ minps,
    const float* __restrict__ topps, const int* __restrict__ topks,
    const float* __restrict__ us, int* __restrict__ out, int V)
{
    const int b = blockIdx.x, tid = threadIdx.x;
    __shared__ u64 cand[CAND_MAX];
    __shared__ unsigned h[NBF + 1];
    __shared__ float wsum[NWF];
    __shared__ unsigned wfirst[NWF];
    __shared__ float s_m, s_den;
    __shared__ int s_thri;
    __shared__ unsigned s_cnt, s_n, s_tot;

    const float t = temps[b];
    const int tk0 = topks[b];
    const unsigned tk0u = (unsigned)tk0;

    // wave 0: row max (slow path only) + raw denom + total/overflow
    if (tid < 64) {
        const int lane = tid;
        float v = (lane < S) ? gmax[b * S + lane] : -INFINITY;
        float vv = v;
        for (int off = 32; off > 0; off >>= 1) vv = fmaxf(vv, __shfl_xor(vv, off));
        const float m = vv / t;
        float d = (lane < S) ? gsum[b * S + lane] : 0.f;    // raw, no e^{-m}
        for (int off = 32; off > 0; off >>= 1) d += __shfl_xor(d, off);
        unsigned cs = (lane < S) ? gcnt16[b * S + lane] : 0u;
        unsigned ov = (cs > (unsigned)SEGCAP) ? 1u : 0u;
        unsigned tot = cs;
        for (int off = 32; off > 0; off >>= 1) { tot += __shfl_xor(tot, off); ov |= __shfl_xor(ov, off); }
        if (lane == 0) { s_m = m; s_den = d; s_tot = tot | (ov ? 0x80000000u : 0u); }
    }
    for (int i = tid; i <= NBF; i += NTF) h[i] = 0u;
    if (tid == 0) { s_cnt = 0u; s_thri = -1; }
    __syncthreads();
    const float m = s_m, denom = s_den;
    const unsigned totw = s_tot;
    const bool fast = !(totw & 0x80000000u) && totw >= tk0u
                      && isfinite(denom) && denom > 0.f;

    int n;
    if (fast) {
        // ---- candidates -> registers (fixed 4/thread, sentinel-skip) + fine hist ----
        const u64* src = gcand + (size_t)b * CAND_MAX;
        u64 myc[CAND_MAX / NTF];
        int mykf[CAND_MAX / NTF];
        #pragma unroll
        for (int k = 0; k < CAND_MAX / NTF; ++k) {
            u64 w = src[tid + k * NTF];
            myc[k] = w; mykf[k] = -1;
            if (w != 0ULL) {
                unsigned fk = ((unsigned)(w >> 32)) | 0x80000000u;  // fkey (x>0)
                unsigned kf = (fk - KBASE) >> FSHIFT;
                if (kf > (unsigned)(NBF - 1)) kf = NBF - 1;
                mykf[k] = (int)kf;
                atomicAdd(&h[kf], 1u);
            }
        }
        __syncthreads();

        // ---- block suffix-scan over h[0..NBF): h[bin] <- count above bin ----
        const int lane = tid & 63, wv = tid >> 6;
        unsigned cnt8[8];
        const int b0 = tid * 8;
        unsigned L = 0;
        #pragma unroll
        for (int j = 0; j < 8; ++j) { cnt8[j] = h[b0 + j]; L += cnt8[j]; }
        unsigned tsuf = L;
        #pragma unroll
        for (int off = 1; off < 64; off <<= 1) {
            unsigned o = __shfl_down(tsuf, off);
            if (lane + off < 64) tsuf += o;
        }
        if (lane == 0) wfirst[wv] = tsuf;
        __syncthreads();
        if (tid < 64) {
            unsigned sv = (tid < NWF) ? wfirst[tid] : 0u;
            #pragma unroll
            for (int off = 1; off < NWF; off <<= 1) {
                unsigned o = __shfl_down(sv, off);
                if (tid + off < NWF) sv += o;
            }
            if (tid < NWF) wfirst[tid] = sv;   // inclusive suffix of wave sums
        }
        __syncthreads();
        unsigned above = tsuf - L + ((wv + 1 < NWF) ? wfirst[wv + 1] : 0u);
        unsigned run = above;
        int mythr = -1;
        #pragma unroll
        for (int j = 7; j >= 0; --j) {
            unsigned incl = run + cnt8[j];
            if (mythr < 0 && incl >= tk0u) mythr = b0 + j;
            h[b0 + j] = run;
            run = incl;
        }
        __syncthreads();
        if (mythr >= 0) atomicMax(&s_thri, mythr);
        __syncthreads();
        const int thrbin = s_thri;
        if ((thrbin >> 3) == tid) s_n = h[thrbin] + cnt8[thrbin & 7];
        __syncthreads();
        n = (int)s_n;

        // ---- scatter: p = exp(x/t)/denom (raw, no shift), dest via per-bin atomic ----
        #pragma unroll
        for (int k = 0; k < CAND_MAX / NTF; ++k) {
            if (mykf[k] >= thrbin) {
                unsigned ub = (unsigned)(myc[k] >> 32);
                float x = __uint_as_float(ub);
                float p = expf(x / t) / denom;
                unsigned dest = atomicAdd(&h[mykf[k]], 1u);
                if (dest < (unsigned)CAND_MAX)
                    cand[dest] = ((u64)__float_as_uint(p) << 32) | (unsigned)(~(unsigned)myc[k]);
            }
        }
        __syncthreads();

        // ---- fixup: insertion-sort multi-element bins (desc by composite) ----
        for (int bb = thrbin + tid; bb < NBF; bb += NTF) {
            unsigned endo = h[bb];          // post-scatter = start + cnt
            unsigned starto = h[bb + 1];    // = start of bin bb
            if (endo > starto + 1 && starto < tk0u) {
                for (unsigned ii = starto + 1; ii < endo; ++ii) {
                    u64 key = cand[ii];
                    unsigned jj = ii;
                    while (jj > starto && cand[jj - 1] < key) { cand[jj] = cand[jj - 1]; --jj; }
                    cand[jj] = key;
                }
            }
        }
        __syncthreads();
    } else {
        // ---- slow path (adversarial only): full hist + denom + rescan + bitonic ----
        const int lane = tid & 63, wv = tid >> 6;
        const float* xrow = logits + (size_t)b * (size_t)V;
        const float4* x4 = (const float4*)xrow;
        const int n4 = V >> 2;
        float lsum = 0.f;
        for (int i = tid; i < n4; i += NTF) {
            float4 v = x4[i];
            lsum += expf(v.x / t - m); lsum += expf(v.y / t - m);
            lsum += expf(v.z / t - m); lsum += expf(v.w / t - m);
            atomicAdd(&h[fkey(v.x) >> KSHIFT], 1u);
            atomicAdd(&h[fkey(v.y) >> KSHIFT], 1u);
            atomicAdd(&h[fkey(v.z) >> KSHIFT], 1u);
            atomicAdd(&h[fkey(v.w) >> KSHIFT], 1u);
        }
        for (int i = (n4 << 2) + tid; i < V; i += NTF) {
            lsum += expf(xrow[i] / t - m);
            atomicAdd(&h[fkey(xrow[i]) >> KSHIFT], 1u);
        }
        for (int off = 32; off > 0; off >>= 1) lsum += __shfl_xor(lsum, off);
        if (lane == 0) wsum[wv] = lsum;
        __syncthreads();
        if (tid == 0) {
            float d = 0.f;
            for (int w = 0; w < NWF; ++w) d += wsum[w];
            s_den = d;
        }
        __syncthreads();
        const float den2 = s_den;
        if (tid < 64) {
            const unsigned needed = tk0u;
            const int CH = NBF / 64;
            const int base = tid * CH;
            unsigned c = 0;
            for (int j = 0; j < CH; ++j) c += h[base + j];
            unsigned tsuf = c;
            for (int off = 1; off < 64; off <<= 1) {
                unsigned o = __shfl_down(tsuf, off);
                if (tid + off < 64) tsuf += o;
            }
            u64 mask = __ballot(tsuf >= needed);
            int lstar = 63 - __builtin_clzll(mask);
            unsigned above = __shfl(tsuf, (lstar + 1) & 63);
            if (lstar == 63) above = 0u;
            if (tid == 0) {
                unsigned run = above;
                int thrb = lstar * CH;
                for (int bb2 = lstar * CH + CH - 1; bb2 >= lstar * CH; --bb2) {
                    run += h[bb2];
                    if (run >= needed) { thrb = bb2; break; }
                }
                s_thri = thrb;
            }
        }
        __syncthreads();
        const unsigned thr = (unsigned)s_thri << KSHIFT;
        for (int i = tid; i < n4; i += NTF) {
            float4 v = x4[i];
            const int i0 = i << 2;
            #pragma unroll
            for (int c = 0; c < 4; ++c) {
                float x = (c == 0) ? v.x : (c == 1) ? v.y : (c == 2) ? v.z : v.w;
                if (fkey(x) >= thr) {
                    float p = expf(x / t - m) / den2;
                    unsigned pos = atomicAdd(&s_cnt, 1u);
                    if (pos < CAND_MAX)
                        cand[pos] = ((u64)__float_as_uint(p) << 32) | (unsigned)(~(unsigned)(i0 + c));
                }
            }
        }
        for (int i = (n4 << 2) + tid; i < V; i += NTF) {
            float x = xrow[i];
            if (fkey(x) >= thr) {
                float p = expf(x / t - m) / den2;
                unsigned pos = atomicAdd(&s_cnt, 1u);
                if (pos < CAND_MAX)
                    cand[pos] = ((u64)__float_as_uint(p) << 32) | (unsigned)(~(unsigned)i);
            }
        }
        __syncthreads();
        n = (int)min(s_cnt, (unsigned)CAND_MAX);
        int n2 = 1; while (n2 < n) n2 <<= 1;
        for (int i = n + tid; i < n2; i += NTF) cand[i] = 0ULL;
        __syncthreads();
        for (int k = 2; k <= n2; k <<= 1) {
            for (int j = k >> 1; j > 0; j >>= 1) {
                for (int i = tid; i < n2; i += NTF) {
                    int ixj = i ^ j;
                    if (ixj > i) {
                        u64 a = cand[i], bb2 = cand[ixj];
                        bool sw = ((i & k) == 0) ? (a < bb2) : (a > bb2);
                        if (sw) { cand[i] = bb2; cand[ixj] = a; }
                    }
                }
                __syncthreads();
            }
        }
    }

    // ---- parallel epilogue: thread i owns sorted element i ----
    const int lane = tid & 63, wv = tid >> 6;
    const float topp = topps[b], minp = minps[b], uu = us[b];
    int tk = tk0;
    if (tk > n) tk = n;
    if (tk > NTF) tk = NTF;

    float p = 0.f;
    if (tid < tk) p = __uint_as_float((unsigned)(cand[tid] >> 32));

    float c = p;
    #pragma unroll
    for (int off = 1; off < 64; off <<= 1) {
        float o = __shfl_up(c, off);
        if (lane >= off) c += o;
    }
    if (lane == 63) wsum[wv] = c;
    __syncthreads();
    if (tid < 64) {
        float sv = (tid < NWF) ? wsum[tid] : 0.f;
        #pragma unroll
        for (int off = 1; off < NWF; off <<= 1) {
            float o = __shfl_up(sv, off);
            if (tid >= off) sv += o;
        }
        if (tid < NWF) wsum[tid] = sv;
    }
    __syncthreads();
    float cum = c + ((wv > 0) ? wsum[wv - 1] : 0.f);
    float excl = cum - p;                       // replicate (cumsum - p) rounding shape
    float p0 = __uint_as_float((unsigned)(cand[0] >> 32));
    float thrmp = p0 * minp;
    float p1v = (excl <= topp) ? p : 0.f;
    float v = (p1v >= thrmp) ? p1v : 0.f;
    __syncthreads();

    float cv = v;
    #pragma unroll
    for (int off = 1; off < 64; off <<= 1) {
        float o = __shfl_up(cv, off);
        if (lane >= off) cv += o;
    }
    if (lane == 63) wsum[wv] = cv;
    __syncthreads();
    if (tid < 64) {
        float sv = (tid < NWF) ? wsum[tid] : 0.f;
        #pragma unroll
        for (int off = 1; off < NWF; off <<= 1) {
            float o = __shfl_up(sv, off);
            if (tid >= off) sv += o;
        }
        if (tid < NWF) wsum[tid] = sv;
    }
    __syncthreads();
    float cdf = cv + ((wv > 0) ? wsum[wv - 1] : 0.f);
    float total = wsum[NWF - 1];
    float target = uu * total;

    bool hit = (tid < tk) && (cdf > target);
    u64 mk = __ballot(hit);
    if (lane == 0) wfirst[wv] = mk ? (unsigned)__builtin_ctzll(mk) : 0xFFFFFFFFu;
    __syncthreads();
    if (tid == 0) {
        int sel = -1;
        for (int w = 0; w < NWF; ++w)
            if (wfirst[w] != 0xFFFFFFFFu) { sel = w * 64 + (int)wfirst[w]; break; }
        if (sel < 0) sel = 0;
        out[b] = (int)~(unsigned)cand[sel];
    }
}

// ---------------- Fallback: monolithic single kernel (round-1, passed) ----------------
#define FNT 512
#define FNBINS 1024
#define FKMARGIN 1224
__global__ __launch_bounds__(FNT) void sampler_mono(
    const float* __restrict__ logits, const float* __restrict__ temps,
    const float* __restrict__ minps, const float* __restrict__ topps,
    const int* __restrict__ topks, const float* __restrict__ us,
    int* __restrict__ out, int V)
{
    const int row = blockIdx.x;
    const int tid = threadIdx.x;
    const float t = temps[row];
    __shared__ unsigned int hist[FNBINS];
    __shared__ u64 cand[CAND_MAX];
    __shared__ float red[FNT / 64];
    __shared__ float s_m, s_denom;
    __shared__ unsigned s_thr, s_cnt;
    for (int i = tid; i < FNBINS; i += FNT) hist[i] = 0u;
    if (tid == 0) s_cnt = 0u;
    const float* xrow = logits + (size_t)row * (size_t)V;
    const int n4 = V >> 2;
    const float4* x4 = (const float4*)xrow;
    float lmax = -INFINITY;
    for (int i = tid; i < n4; i += FNT) {
        float4 v = x4[i];
        lmax = fmaxf(lmax, fmaxf(fmaxf(v.x, v.y), fmaxf(v.z, v.w)));
    }
    for (int i = (n4 << 2) + tid; i < V; i += FNT) lmax = fmaxf(lmax, xrow[i]);
    for (int off = 32; off > 0; off >>= 1) lmax = fmaxf(lmax, __shfl_xor(lmax, off));
    if ((tid & 63) == 0) red[tid >> 6] = lmax;
    __syncthreads();
    if (tid == 0) {
        float r = red[0];
        for (int w = 1; w < FNT / 64; ++w) r = fmaxf(r, red[w]);
        s_m = r / t;
    }
    __syncthreads();
    const float m = s_m;
    float lsum = 0.f;
    for (int i = tid; i < n4; i += FNT) {
        float4 v = x4[i];
        float e0 = expf(v.x / t - m), e1 = expf(v.y / t - m);
        float e2 = expf(v.z / t - m), e3 = expf(v.w / t - m);
        lsum += e0; lsum += e1; lsum += e2; lsum += e3;
        atomicAdd(&hist[__float_as_uint(e0) >> 20], 1u);
        atomicAdd(&hist[__float_as_uint(e1) >> 20], 1u);
        atomicAdd(&hist[__float_as_uint(e2) >> 20], 1u);
        atomicAdd(&hist[__float_as_uint(e3) >> 20], 1u);
    }
    for (int i = (n4 << 2) + tid; i < V; i += FNT) {
        float e = expf(xrow[i] / t - m);
        lsum += e;
        atomicAdd(&hist[__float_as_uint(e) >> 20], 1u);
    }
    for (int off = 32; off > 0; off >>= 1) lsum += __shfl_xor(lsum, off);
    if ((tid & 63) == 0) red[tid >> 6] = lsum;
    __syncthreads();
    if (tid == 0) {
        float r = 0.f;
        for (int w = 0; w < FNT / 64; ++w) r += red[w];
        s_denom = r;
    }
    __syncthreads();
    const float denom = s_denom;
    if (tid < 64) {
        const int lane = tid;
        const int CH = FNBINS / 64;
        const int base = lane * CH;
        unsigned c = 0;
        #pragma unroll
        for (int j = 0; j < CH; ++j) c += hist[base + j];
        unsigned tsuf = c;
        #pragma unroll
        for (int off = 1; off < 64; off <<= 1) {
            unsigned o = __shfl_down(tsuf, off);
            if (lane + off < 64) tsuf += o;
        }
        unsigned long long mask = __ballot(tsuf >= (unsigned)FKMARGIN);
        int lstar = 63 - __builtin_clzll(mask);
        unsigned above = __shfl(tsuf, (lstar + 1) & 63);
        if (lstar == 63) above = 0u;
        if (lane == 0) {
            unsigned run = above;
            int thrbin = lstar * CH;
            for (int bb = lstar * CH + CH - 1; bb >= lstar * CH; --bb) {
                run += hist[bb];
                if (run >= (unsigned)FKMARGIN) { thrbin = bb; break; }
            }
            s_thr = (unsigned)thrbin << 20;
        }
    }
    __syncthreads();
    const unsigned thrkey = s_thr;
    for (int i = tid; i < n4; i += FNT) {
        float4 v = x4[i];
        float e[4] = { expf(v.x / t - m), expf(v.y / t - m),
                       expf(v.z / t - m), expf(v.w / t - m) };
        #pragma unroll
        for (int c = 0; c < 4; ++c) {
            unsigned eb = __float_as_uint(e[c]);
            if (eb >= thrkey) {
                float p = e[c] / denom;
                unsigned pos = atomicAdd(&s_cnt, 1u);
                if (pos < CAND_MAX)
                    cand[pos] = ((u64)__float_as_uint(p) << 32) | (unsigned)(~(unsigned)((i << 2) + c));
            }
        }
    }
    for (int i = (n4 << 2) + tid; i < V; i += FNT) {
        float e = expf(xrow[i] / t - m);
        if (__float_as_uint(e) >= thrkey) {
            float p = e / denom;
            unsigned pos = atomicAdd(&s_cnt, 1u);
            if (pos < CAND_MAX)
                cand[pos] = ((u64)__float_as_uint(p) << 32) | (unsigned)(~(unsigned)i);
        }
    }
    __syncthreads();
    int n = (int)s_cnt; if (n > CAND_MAX) n = CAND_MAX;
    int n2 = 1; while (n2 < n) n2 <<= 1;
    for (int i = n + tid; i < n2; i += FNT) cand[i] = 0ULL;
    __syncthreads();
    for (int k = 2; k <= n2; k <<= 1) {
        for (int j = k >> 1; j > 0; j >>= 1) {
            for (int i = tid; i < n2; i += FNT) {
                int ixj = i ^ j;
                if (ixj > i) {
                    u64 a = cand[i], bb = cand[ixj];
                    bool sw = ((i & k) == 0) ? (a < bb) : (a > bb);
                    if (sw) { cand[i] = bb; cand[ixj] = a; }
                }
            }
            __syncthreads();
        }
    }
    if (tid == 0) {
        const float topp = topps[row], minp = minps[row], uu = us[row];
        int tk = topks[row];
        if (tk > n) tk = n;
        float p0 = __uint_as_float((unsigned)(cand[0] >> 32));
        float thrmp = p0 * minp;
        float cum = 0.f, total = 0.f;
        for (int i = 0; i < tk; ++i) {
            float p = __uint_as_float((unsigned)(cand[i] >> 32));
            cum = cum + p;
            float excl = cum - p;
            float p1 = (excl <= topp) ? p : 0.f;
            float v = (p1 >= thrmp) ? p1 : 0.f;
            total += v;
        }
        float target = uu * total;
        float cdf = 0.f; int sel = -1;
        cum = 0.f;
        for (int i = 0; i < tk; ++i) {
            float p = __uint_as_float((unsigned)(cand[i] >> 32));
            cum = cum + p;
            float excl = cum - p;
            float p1 = (excl <= topp) ? p : 0.f;
            float v = (p1 >= thrmp) ? p1 : 0.f;
            cdf += v;
            if (cdf > target) { sel = i; break; }
        }
        if (sel < 0) sel = 0;
        out[row] = (int)~(unsigned)cand[sel];
    }
}

extern "C" void kernel_launch(void* const* d_in, const int* in_sizes, int n_in,
                              void* d_out, int out_size, void* d_ws, size_t ws_size,
                              hipStream_t stream) {
    const float* logits = (const float*)d_in[0];
    const float* temps  = (const float*)d_in[1];
    const float* minps  = (const float*)d_in[2];
    const float* topps  = (const float*)d_in[3];
    const int*   topks  = (const int*)d_in[4];
    const float* us     = (const float*)d_in[5];
    const int B = in_sizes[1];
    const int V = in_sizes[0] / B;
    int* outp = (int*)d_out;

    const int slen = (((V + S - 1) / S) + 3) & ~3;   // slice length, mult of 4

    size_t need = 0;
    const size_t off_cand = need; need += (size_t)B * CAND_MAX * sizeof(u64);
    const size_t off_cnt  = need; need += (size_t)B * S * sizeof(unsigned);
    const size_t off_max  = need; need += (size_t)B * S * sizeof(float);
    const size_t off_sum  = need; need += (size_t)B * S * sizeof(float);

    if (ws_size < need) {
        sampler_mono<<<dim3(B), dim3(FNT), 0, stream>>>(
            logits, temps, minps, topps, topks, us, outp, V);
        return;
    }

    char* w = (char*)d_ws;
    u64*      gcand  = (u64*)(w + off_cand);
    unsigned* gcnt16 = (unsigned*)(w + off_cnt);
    float*    gmax   = (float*)(w + off_max);
    float*    gsum   = (float*)(w + off_sum);

    // No workspace zeroing needed: every word read is written this call.
    k_pass1<<<dim3(S, B), dim3(NT1), 0, stream>>>(
        logits, temps, gmax, gsum, gcand, gcnt16, V, slen);
    k_finish<<<dim3(B), dim3(NTF), 0, stream>>>(
        logits, gcand, gcnt16, gmax, gsum, temps, minps, topps, topks, us, outp, V);
}

// Round 16
// 32.149 us; speedup vs baseline: 1.0948x; 1.0948x over previous
//
#include <hip/hip_runtime.h>
#include <hip/hip_bf16.h>
#include <stdint.h>

typedef unsigned long long u64;

#define S 16            // slices per row
#define SEGCAP 256      // per-slice candidate segment (expect ~182, 5.5-sigma safe)
#define NBF 8192        // fine bins for counting sort (range [2,8))
#define KBASE 0xC0000000u   // fkey(2.0f)
#define FSHIFT 11
#define KSHIFT 19       // coarse 13-bit key (slow path)
#define CAND_MAX 4096   // = S * SEGCAP
#define NT1 256
#define NW1 (NT1 / 64)
#define NTF 1024
#define NWF (NTF / 64)

__device__ __forceinline__ unsigned fkey(float x) {
    unsigned u = __float_as_uint(x);
    return ((int)u < 0) ? ~u : (u | 0x80000000u);
}

// ---------------- K1: single sweep: max + raw exp-sum + speculative collect ----
// 2-wide unrolled, dual accumulator chains, native exp (R14-proven config).
__global__ __launch_bounds__(NT1) void k_pass1(
    const float* __restrict__ logits, const float* __restrict__ temps,
    float* __restrict__ gmax, float* __restrict__ gsum,
    u64* __restrict__ gcand, unsigned* __restrict__ gcnt16, int V, int slen)
{
    const int s = blockIdx.x, b = blockIdx.y, tid = threadIdx.x;
    __shared__ u64 buf[SEGCAP];
    __shared__ float redm[NW1], reds[NW1];
    __shared__ unsigned s_cnt;
    if (tid == 0) s_cnt = 0u;
    __syncthreads();

    const float t = temps[b];
    const float invt = 1.0f / t;      // denom-only rounding class (accepted)
    const float* xrow = logits + (size_t)b * (size_t)V;
    const int beg = s * slen, end = min(V, beg + slen);
    const float4* x4 = (const float4*)xrow;
    const int beg4 = beg >> 2, end4 = end >> 2;

    float lmax0 = -INFINITY, lmax1 = -INFINITY;
    float lsum0 = 0.f, lsum1 = 0.f;
    const float4 pad = make_float4(-INFINITY, -INFINITY, -INFINITY, -INFINITY);

    for (int idx = beg4 + tid; idx < end4; idx += 2 * NT1) {
        float4 a = x4[idx];
        const int jb = idx + NT1;
        float4 bv = (jb < end4) ? x4[jb] : pad;    // __expf(-inf)=0, fmax neutral

        lmax0 = fmaxf(lmax0, fmaxf(fmaxf(a.x, a.y), fmaxf(a.z, a.w)));
        lmax1 = fmaxf(lmax1, fmaxf(fmaxf(bv.x, bv.y), fmaxf(bv.z, bv.w)));
        lsum0 += __expf(a.x * invt);  lsum0 += __expf(a.y * invt);
        lsum0 += __expf(a.z * invt);  lsum0 += __expf(a.w * invt);
        lsum1 += __expf(bv.x * invt); lsum1 += __expf(bv.y * invt);
        lsum1 += __expf(bv.z * invt); lsum1 += __expf(bv.w * invt);

        const int i0 = idx << 2;
        if (a.x >= 2.0f) { unsigned p = atomicAdd(&s_cnt, 1u); if (p < SEGCAP) buf[p] = ((u64)__float_as_uint(a.x) << 32) | (unsigned)(i0    ); }
        if (a.y >= 2.0f) { unsigned p = atomicAdd(&s_cnt, 1u); if (p < SEGCAP) buf[p] = ((u64)__float_as_uint(a.y) << 32) | (unsigned)(i0 + 1); }
        if (a.z >= 2.0f) { unsigned p = atomicAdd(&s_cnt, 1u); if (p < SEGCAP) buf[p] = ((u64)__float_as_uint(a.z) << 32) | (unsigned)(i0 + 2); }
        if (a.w >= 2.0f) { unsigned p = atomicAdd(&s_cnt, 1u); if (p < SEGCAP) buf[p] = ((u64)__float_as_uint(a.w) << 32) | (unsigned)(i0 + 3); }
        const int i1 = jb << 2;
        if (bv.x >= 2.0f) { unsigned p = atomicAdd(&s_cnt, 1u); if (p < SEGCAP) buf[p] = ((u64)__float_as_uint(bv.x) << 32) | (unsigned)(i1    ); }
        if (bv.y >= 2.0f) { unsigned p = atomicAdd(&s_cnt, 1u); if (p < SEGCAP) buf[p] = ((u64)__float_as_uint(bv.y) << 32) | (unsigned)(i1 + 1); }
        if (bv.z >= 2.0f) { unsigned p = atomicAdd(&s_cnt, 1u); if (p < SEGCAP) buf[p] = ((u64)__float_as_uint(bv.z) << 32) | (unsigned)(i1 + 2); }
        if (bv.w >= 2.0f) { unsigned p = atomicAdd(&s_cnt, 1u); if (p < SEGCAP) buf[p] = ((u64)__float_as_uint(bv.w) << 32) | (unsigned)(i1 + 3); }
    }
    for (int i = max(beg, end4 << 2) + tid; i < end; i += NT1) {
        float x = xrow[i];
        lmax0 = fmaxf(lmax0, x);
        lsum0 += __expf(x * invt);
        if (x >= 2.0f) { unsigned p = atomicAdd(&s_cnt, 1u); if (p < SEGCAP) buf[p] = ((u64)__float_as_uint(x) << 32) | (unsigned)i; }
    }

    float lmax = fmaxf(lmax0, lmax1);
    float lsum = lsum0 + lsum1;
    for (int off = 32; off > 0; off >>= 1) {
        lmax = fmaxf(lmax, __shfl_xor(lmax, off));
        lsum += __shfl_xor(lsum, off);
    }
    if ((tid & 63) == 0) { redm[tid >> 6] = lmax; reds[tid >> 6] = lsum; }
    __syncthreads();
    if (tid == 0) {
        float m = redm[0], sum = reds[0];
        for (int w = 1; w < NW1; ++w) { m = fmaxf(m, redm[w]); sum += reds[w]; }
        gmax[b * S + s] = m;
        gsum[b * S + s] = sum;            // raw sum of exp(x/t), no max shift
        gcnt16[b * S + s] = s_cnt;        // raw count (> SEGCAP -> slow path)
    }
    __syncthreads();
    const unsigned cw = min(s_cnt, (unsigned)SEGCAP);
    u64* dst = gcand + (size_t)b * CAND_MAX + (size_t)s * SEGCAP;
    for (int i = tid; i < SEGCAP; i += NT1)
        dst[i] = (i < (int)cw) ? buf[i] : 0ULL;   // sentinel-pad the tail
}

// ---------------- K2: per-row finish: counting sort (fast) / rescan+bitonic (slow) ----
__global__ __launch_bounds__(NTF) void k_finish(
    const float* __restrict__ logits, const u64* __restrict__ gcand,
    const unsigned* __restrict__ gcnt16,
    const float* __restrict__ gmax, const float* __restrict__ gsum,
    const float* __restrict__ temps, const float* __restrict__ minps,
    const float* __restrict__ topps, const int* __restrict__ topks,
    const float* __restrict__ us, int* __restrict__ out, int V)
{
    const int b = blockIdx.x, tid = threadIdx.x;
    __shared__ u64 cand[CAND_MAX];
    __shared__ unsigned h[NBF + 1];
    __shared__ float wsum[NWF];
    __shared__ unsigned wfirst[NWF];
    __shared__ float s_m, s_den;
    __shared__ int s_thri;
    __shared__ unsigned s_cnt, s_n, s_tot;

    // ---- T14 async-stage: issue candidate loads FIRST; latency hides under
    // the wave-0 reductions + 8K-word LDS zeroing below. Always safe: pass1
    // writes every gcand word each call.
    const u64* src = gcand + (size_t)b * CAND_MAX;
    u64 myc[CAND_MAX / NTF];
    #pragma unroll
    for (int k = 0; k < CAND_MAX / NTF; ++k)
        myc[k] = src[tid + k * NTF];

    const float t = temps[b];
    const int tk0 = topks[b];
    const unsigned tk0u = (unsigned)tk0;

    // wave 0: row max (slow path only) + raw denom + total/overflow
    if (tid < 64) {
        const int lane = tid;
        float v = (lane < S) ? gmax[b * S + lane] : -INFINITY;
        float vv = v;
        for (int off = 32; off > 0; off >>= 1) vv = fmaxf(vv, __shfl_xor(vv, off));
        const float m = vv / t;
        float d = (lane < S) ? gsum[b * S + lane] : 0.f;    // raw, no e^{-m}
        for (int off = 32; off > 0; off >>= 1) d += __shfl_xor(d, off);
        unsigned cs = (lane < S) ? gcnt16[b * S + lane] : 0u;
        unsigned ov = (cs > (unsigned)SEGCAP) ? 1u : 0u;
        unsigned tot = cs;
        for (int off = 32; off > 0; off >>= 1) { tot += __shfl_xor(tot, off); ov |= __shfl_xor(ov, off); }
        if (lane == 0) { s_m = m; s_den = d; s_tot = tot | (ov ? 0x80000000u : 0u); }
    }
    for (int i = tid; i <= NBF; i += NTF) h[i] = 0u;
    if (tid == 0) { s_cnt = 0u; s_thri = -1; }
    __syncthreads();
    const float m = s_m, denom = s_den;
    const unsigned totw = s_tot;
    const bool fast = !(totw & 0x80000000u) && totw >= tk0u
                      && isfinite(denom) && denom > 0.f;

    int n;
    if (fast) {
        // ---- fine histogram from preloaded registers (sentinel-skip) ----
        int mykf[CAND_MAX / NTF];
        #pragma unroll
        for (int k = 0; k < CAND_MAX / NTF; ++k) {
            mykf[k] = -1;
            if (myc[k] != 0ULL) {
                unsigned fk = ((unsigned)(myc[k] >> 32)) | 0x80000000u;  // fkey (x>0)
                unsigned kf = (fk - KBASE) >> FSHIFT;
                if (kf > (unsigned)(NBF - 1)) kf = NBF - 1;
                mykf[k] = (int)kf;
                atomicAdd(&h[kf], 1u);
            }
        }
        __syncthreads();

        // ---- block suffix-scan over h[0..NBF): h[bin] <- count above bin ----
        const int lane = tid & 63, wv = tid >> 6;
        unsigned cnt8[8];
        const int b0 = tid * 8;
        unsigned L = 0;
        #pragma unroll
        for (int j = 0; j < 8; ++j) { cnt8[j] = h[b0 + j]; L += cnt8[j]; }
        unsigned tsuf = L;
        #pragma unroll
        for (int off = 1; off < 64; off <<= 1) {
            unsigned o = __shfl_down(tsuf, off);
            if (lane + off < 64) tsuf += o;
        }
        if (lane == 0) wfirst[wv] = tsuf;
        __syncthreads();
        if (tid < 64) {
            unsigned sv = (tid < NWF) ? wfirst[tid] : 0u;
            #pragma unroll
            for (int off = 1; off < NWF; off <<= 1) {
                unsigned o = __shfl_down(sv, off);
                if (tid + off < NWF) sv += o;
            }
            if (tid < NWF) wfirst[tid] = sv;   // inclusive suffix of wave sums
        }
        __syncthreads();
        unsigned above = tsuf - L + ((wv + 1 < NWF) ? wfirst[wv + 1] : 0u);
        unsigned run = above;
        int mythr = -1;
        #pragma unroll
        for (int j = 7; j >= 0; --j) {
            unsigned incl = run + cnt8[j];
            if (mythr < 0 && incl >= tk0u) mythr = b0 + j;
            h[b0 + j] = run;
            run = incl;
        }
        __syncthreads();
        if (mythr >= 0) atomicMax(&s_thri, mythr);
        __syncthreads();
        const int thrbin = s_thri;
        if ((thrbin >> 3) == tid) s_n = h[thrbin] + cnt8[thrbin & 7];
        __syncthreads();
        n = (int)s_n;

        // ---- scatter: p = exp(x/t)/denom (raw, no shift), dest via per-bin atomic ----
        #pragma unroll
        for (int k = 0; k < CAND_MAX / NTF; ++k) {
            if (mykf[k] >= thrbin) {
                unsigned ub = (unsigned)(myc[k] >> 32);
                float x = __uint_as_float(ub);
                float p = expf(x / t) / denom;
                unsigned dest = atomicAdd(&h[mykf[k]], 1u);
                if (dest < (unsigned)CAND_MAX)
                    cand[dest] = ((u64)__float_as_uint(p) << 32) | (unsigned)(~(unsigned)myc[k]);
            }
        }
        __syncthreads();

        // ---- fixup: insertion-sort multi-element bins (desc by composite) ----
        for (int bb = thrbin + tid; bb < NBF; bb += NTF) {
            unsigned endo = h[bb];          // post-scatter = start + cnt
            unsigned starto = h[bb + 1];    // = start of bin bb
            if (endo > starto + 1 && starto < tk0u) {
                for (unsigned ii = starto + 1; ii < endo; ++ii) {
                    u64 key = cand[ii];
                    unsigned jj = ii;
                    while (jj > starto && cand[jj - 1] < key) { cand[jj] = cand[jj - 1]; --jj; }
                    cand[jj] = key;
                }
            }
        }
        __syncthreads();
    } else {
        // ---- slow path (adversarial only): full hist + denom + rescan + bitonic ----
        const int lane = tid & 63, wv = tid >> 6;
        const float* xrow = logits + (size_t)b * (size_t)V;
        const float4* x4 = (const float4*)xrow;
        const int n4 = V >> 2;
        float lsum = 0.f;
        for (int i = tid; i < n4; i += NTF) {
            float4 v = x4[i];
            lsum += expf(v.x / t - m); lsum += expf(v.y / t - m);
            lsum += expf(v.z / t - m); lsum += expf(v.w / t - m);
            atomicAdd(&h[fkey(v.x) >> KSHIFT], 1u);
            atomicAdd(&h[fkey(v.y) >> KSHIFT], 1u);
            atomicAdd(&h[fkey(v.z) >> KSHIFT], 1u);
            atomicAdd(&h[fkey(v.w) >> KSHIFT], 1u);
        }
        for (int i = (n4 << 2) + tid; i < V; i += NTF) {
            lsum += expf(xrow[i] / t - m);
            atomicAdd(&h[fkey(xrow[i]) >> KSHIFT], 1u);
        }
        for (int off = 32; off > 0; off >>= 1) lsum += __shfl_xor(lsum, off);
        if (lane == 0) wsum[wv] = lsum;
        __syncthreads();
        if (tid == 0) {
            float d = 0.f;
            for (int w = 0; w < NWF; ++w) d += wsum[w];
            s_den = d;
        }
        __syncthreads();
        const float den2 = s_den;
        if (tid < 64) {
            const unsigned needed = tk0u;
            const int CH = NBF / 64;
            const int base = tid * CH;
            unsigned c = 0;
            for (int j = 0; j < CH; ++j) c += h[base + j];
            unsigned tsuf = c;
            for (int off = 1; off < 64; off <<= 1) {
                unsigned o = __shfl_down(tsuf, off);
                if (tid + off < 64) tsuf += o;
            }
            u64 mask = __ballot(tsuf >= needed);
            int lstar = 63 - __builtin_clzll(mask);
            unsigned above = __shfl(tsuf, (lstar + 1) & 63);
            if (lstar == 63) above = 0u;
            if (tid == 0) {
                unsigned run = above;
                int thrb = lstar * CH;
                for (int bb2 = lstar * CH + CH - 1; bb2 >= lstar * CH; --bb2) {
                    run += h[bb2];
                    if (run >= needed) { thrb = bb2; break; }
                }
                s_thri = thrb;
            }
        }
        __syncthreads();
        const unsigned thr = (unsigned)s_thri << KSHIFT;
        for (int i = tid; i < n4; i += NTF) {
            float4 v = x4[i];
            const int i0 = i << 2;
            #pragma unroll
            for (int c = 0; c < 4; ++c) {
                float x = (c == 0) ? v.x : (c == 1) ? v.y : (c == 2) ? v.z : v.w;
                if (fkey(x) >= thr) {
                    float p = expf(x / t - m) / den2;
                    unsigned pos = atomicAdd(&s_cnt, 1u);
                    if (pos < CAND_MAX)
                        cand[pos] = ((u64)__float_as_uint(p) << 32) | (unsigned)(~(unsigned)(i0 + c));
                }
            }
        }
        for (int i = (n4 << 2) + tid; i < V; i += NTF) {
            float x = xrow[i];
            if (fkey(x) >= thr) {
                float p = expf(x / t - m) / den2;
                unsigned pos = atomicAdd(&s_cnt, 1u);
                if (pos < CAND_MAX)
                    cand[pos] = ((u64)__float_as_uint(p) << 32) | (unsigned)(~(unsigned)i);
            }
        }
        __syncthreads();
        n = (int)min(s_cnt, (unsigned)CAND_MAX);
        int n2 = 1; while (n2 < n) n2 <<= 1;
        for (int i = n + tid; i < n2; i += NTF) cand[i] = 0ULL;
        __syncthreads();
        for (int k = 2; k <= n2; k <<= 1) {
            for (int j = k >> 1; j > 0; j >>= 1) {
                for (int i = tid; i < n2; i += NTF) {
                    int ixj = i ^ j;
                    if (ixj > i) {
                        u64 a = cand[i], bb2 = cand[ixj];
                        bool sw = ((i & k) == 0) ? (a < bb2) : (a > bb2);
                        if (sw) { cand[i] = bb2; cand[ixj] = a; }
                    }
                }
                __syncthreads();
            }
        }
    }

    // ---- parallel epilogue: thread i owns sorted element i ----
    const int lane = tid & 63, wv = tid >> 6;
    const float topp = topps[b], minp = minps[b], uu = us[b];
    int tk = tk0;
    if (tk > n) tk = n;
    if (tk > NTF) tk = NTF;

    float p = 0.f;
    if (tid < tk) p = __uint_as_float((unsigned)(cand[tid] >> 32));

    float c = p;
    #pragma unroll
    for (int off = 1; off < 64; off <<= 1) {
        float o = __shfl_up(c, off);
        if (lane >= off) c += o;
    }
    if (lane == 63) wsum[wv] = c;
    __syncthreads();
    if (tid < 64) {
        float sv = (tid < NWF) ? wsum[tid] : 0.f;
        #pragma unroll
        for (int off = 1; off < NWF; off <<= 1) {
            float o = __shfl_up(sv, off);
            if (tid >= off) sv += o;
        }
        if (tid < NWF) wsum[tid] = sv;
    }
    __syncthreads();
    float cum = c + ((wv > 0) ? wsum[wv - 1] : 0.f);
    float excl = cum - p;                       // replicate (cumsum - p) rounding shape
    float p0 = __uint_as_float((unsigned)(cand[0] >> 32));
    float thrmp = p0 * minp;
    float p1v = (excl <= topp) ? p : 0.f;
    float v = (p1v >= thrmp) ? p1v : 0.f;
    __syncthreads();

    float cv = v;
    #pragma unroll
    for (int off = 1; off < 64; off <<= 1) {
        float o = __shfl_up(cv, off);
        if (lane >= off) cv += o;
    }
    if (lane == 63) wsum[wv] = cv;
    __syncthreads();
    if (tid < 64) {
        float sv = (tid < NWF) ? wsum[tid] : 0.f;
        #pragma unroll
        for (int off = 1; off < NWF; off <<= 1) {
            float o = __shfl_up(sv, off);
            if (tid >= off) sv += o;
        }
        if (tid < NWF) wsum[tid] = sv;
    }
    __syncthreads();
    float cdf = cv + ((wv > 0) ? wsum[wv - 1] : 0.f);
    float total = wsum[NWF - 1];
    float target = uu * total;

    bool hit = (tid < tk) && (cdf > target);
    u64 mk = __ballot(hit);
    if (lane == 0) wfirst[wv] = mk ? (unsigned)__builtin_ctzll(mk) : 0xFFFFFFFFu;
    __syncthreads();
    if (tid == 0) {
        int sel = -1;
        for (int w = 0; w < NWF; ++w)
            if (wfirst[w] != 0xFFFFFFFFu) { sel = w * 64 + (int)wfirst[w]; break; }
        if (sel < 0) sel = 0;
        out[b] = (int)~(unsigned)cand[sel];
    }
}

// ---------------- Fallback: monolithic single kernel (round-1, passed) ----------------
#define FNT 512
#define FNBINS 1024
#define FKMARGIN 1224
__global__ __launch_bounds__(FNT) void sampler_mono(
    const float* __restrict__ logits, const float* __restrict__ temps,
    const float* __restrict__ minps, const float* __restrict__ topps,
    const int* __restrict__ topks, const float* __restrict__ us,
    int* __restrict__ out, int V)
{
    const int row = blockIdx.x;
    const int tid = threadIdx.x;
    const float t = temps[row];
    __shared__ unsigned int hist[FNBINS];
    __shared__ u64 cand[CAND_MAX];
    __shared__ float red[FNT / 64];
    __shared__ float s_m, s_denom;
    __shared__ unsigned s_thr, s_cnt;
    for (int i = tid; i < FNBINS; i += FNT) hist[i] = 0u;
    if (tid == 0) s_cnt = 0u;
    const float* xrow = logits + (size_t)row * (size_t)V;
    const int n4 = V >> 2;
    const float4* x4 = (const float4*)xrow;
    float lmax = -INFINITY;
    for (int i = tid; i < n4; i += FNT) {
        float4 v = x4[i];
        lmax = fmaxf(lmax, fmaxf(fmaxf(v.x, v.y), fmaxf(v.z, v.w)));
    }
    for (int i = (n4 << 2) + tid; i < V; i += FNT) lmax = fmaxf(lmax, xrow[i]);
    for (int off = 32; off > 0; off >>= 1) lmax = fmaxf(lmax, __shfl_xor(lmax, off));
    if ((tid & 63) == 0) red[tid >> 6] = lmax;
    __syncthreads();
    if (tid == 0) {
        float r = red[0];
        for (int w = 1; w < FNT / 64; ++w) r = fmaxf(r, red[w]);
        s_m = r / t;
    }
    __syncthreads();
    const float m = s_m;
    float lsum = 0.f;
    for (int i = tid; i < n4; i += FNT) {
        float4 v = x4[i];
        float e0 = expf(v.x / t - m), e1 = expf(v.y / t - m);
        float e2 = expf(v.z / t - m), e3 = expf(v.w / t - m);
        lsum += e0; lsum += e1; lsum += e2; lsum += e3;
        atomicAdd(&hist[__float_as_uint(e0) >> 20], 1u);
        atomicAdd(&hist[__float_as_uint(e1) >> 20], 1u);
        atomicAdd(&hist[__float_as_uint(e2) >> 20], 1u);
        atomicAdd(&hist[__float_as_uint(e3) >> 20], 1u);
    }
    for (int i = (n4 << 2) + tid; i < V; i += FNT) {
        float e = expf(xrow[i] / t - m);
        lsum += e;
        atomicAdd(&hist[__float_as_uint(e) >> 20], 1u);
    }
    for (int off = 32; off > 0; off >>= 1) lsum += __shfl_xor(lsum, off);
    if ((tid & 63) == 0) red[tid >> 6] = lsum;
    __syncthreads();
    if (tid == 0) {
        float r = 0.f;
        for (int w = 0; w < FNT / 64; ++w) r += red[w];
        s_denom = r;
    }
    __syncthreads();
    const float denom = s_denom;
    if (tid < 64) {
        const int lane = tid;
        const int CH = FNBINS / 64;
        const int base = lane * CH;
        unsigned c = 0;
        #pragma unroll
        for (int j = 0; j < CH; ++j) c += hist[base + j];
        unsigned tsuf = c;
        #pragma unroll
        for (int off = 1; off < 64; off <<= 1) {
            unsigned o = __shfl_down(tsuf, off);
            if (lane + off < 64) tsuf += o;
        }
        unsigned long long mask = __ballot(tsuf >= (unsigned)FKMARGIN);
        int lstar = 63 - __builtin_clzll(mask);
        unsigned above = __shfl(tsuf, (lstar + 1) & 63);
        if (lstar == 63) above = 0u;
        if (lane == 0) {
            unsigned run = above;
            int thrbin = lstar * CH;
            for (int bb = lstar * CH + CH - 1; bb >= lstar * CH; --bb) {
                run += hist[bb];
                if (run >= (unsigned)FKMARGIN) { thrbin = bb; break; }
            }
            s_thr = (unsigned)thrbin << 20;
        }
    }
    __syncthreads();
    const unsigned thrkey = s_thr;
    for (int i = tid; i < n4; i += FNT) {
        float4 v = x4[i];
        float e[4] = { expf(v.x / t - m), expf(v.y / t - m),
                       expf(v.z / t - m), expf(v.w / t - m) };
        #pragma unroll
        for (int c = 0; c < 4; ++c) {
            unsigned eb = __float_as_uint(e[c]);
            if (eb >= thrkey) {
                float p = e[c] / denom;
                unsigned pos = atomicAdd(&s_cnt, 1u);
                if (pos < CAND_MAX)
                    cand[pos] = ((u64)__float_as_uint(p) << 32) | (unsigned)(~(unsigned)((i << 2) + c));
            }
        }
    }
    for (int i = (n4 << 2) + tid; i < V; i += FNT) {
        float e = expf(xrow[i] / t - m);
        if (__float_as_uint(e) >= thrkey) {
            float p = e / denom;
            unsigned pos = atomicAdd(&s_cnt, 1u);
            if (pos < CAND_MAX)
                cand[pos] = ((u64)__float_as_uint(p) << 32) | (unsigned)(~(unsigned)i);
        }
    }
    __syncthreads();
    int n = (int)s_cnt; if (n > CAND_MAX) n = CAND_MAX;
    int n2 = 1; while (n2 < n) n2 <<= 1;
    for (int i = n + tid; i < n2; i += FNT) cand[i] = 0ULL;
    __syncthreads();
    for (int k = 2; k <= n2; k <<= 1) {
        for (int j = k >> 1; j > 0; j >>= 1) {
            for (int i = tid; i < n2; i += FNT) {
                int ixj = i ^ j;
                if (ixj > i) {
                    u64 a = cand[i], bb = cand[ixj];
                    bool sw = ((i & k) == 0) ? (a < bb) : (a > bb);
                    if (sw) { cand[i] = bb; cand[ixj] = a; }
                }
            }
            __syncthreads();
        }
    }
    if (tid == 0) {
        const float topp = topps[row], minp = minps[row], uu = us[row];
        int tk = topks[row];
        if (tk > n) tk = n;
        float p0 = __uint_as_float((unsigned)(cand[0] >> 32));
        float thrmp = p0 * minp;
        float cum = 0.f, total = 0.f;
        for (int i = 0; i < tk; ++i) {
            float p = __uint_as_float((unsigned)(cand[i] >> 32));
            cum = cum + p;
            float excl = cum - p;
            float p1 = (excl <= topp) ? p : 0.f;
            float v = (p1 >= thrmp) ? p1 : 0.f;
            total += v;
        }
        float target = uu * total;
        float cdf = 0.f; int sel = -1;
        cum = 0.f;
        for (int i = 0; i < tk; ++i) {
            float p = __uint_as_float((unsigned)(cand[i] >> 32));
            cum = cum + p;
            float excl = cum - p;
            float p1 = (excl <= topp) ? p : 0.f;
            float v = (p1 >= thrmp) ? p1 : 0.f;
            cdf += v;
            if (cdf > target) { sel = i; break; }
        }
        if (sel < 0) sel = 0;
        out[row] = (int)~(unsigned)cand[sel];
    }
}

extern "C" void kernel_launch(void* const* d_in, const int* in_sizes, int n_in,
                              void* d_out, int out_size, void* d_ws, size_t ws_size,
                              hipStream_t stream) {
    const float* logits = (const float*)d_in[0];
    const float* temps  = (const float*)d_in[1];
    const float* minps  = (const float*)d_in[2];
    const float* topps  = (const float*)d_in[3];
    const int*   topks  = (const int*)d_in[4];
    const float* us     = (const float*)d_in[5];
    const int B = in_sizes[1];
    const int V = in_sizes[0] / B;
    int* outp = (int*)d_out;

    const int slen = (((V + S - 1) / S) + 3) & ~3;   // slice length, mult of 4

    size_t need = 0;
    const size_t off_cand = need; need += (size_t)B * CAND_MAX * sizeof(u64);
    const size_t off_cnt  = need; need += (size_t)B * S * sizeof(unsigned);
    const size_t off_max  = need; need += (size_t)B * S * sizeof(float);
    const size_t off_sum  = need; need += (size_t)B * S * sizeof(float);

    if (ws_size < need) {
        sampler_mono<<<dim3(B), dim3(FNT), 0, stream>>>(
            logits, temps, minps, topps, topks, us, outp, V);
        return;
    }

    char* w = (char*)d_ws;
    u64*      gcand  = (u64*)(w + off_cand);
    unsigned* gcnt16 = (unsigned*)(w + off_cnt);
    float*    gmax   = (float*)(w + off_max);
    float*    gsum   = (float*)(w + off_sum);

    // No workspace zeroing needed: every word read is written this call.
    k_pass1<<<dim3(S, B), dim3(NT1), 0, stream>>>(
        logits, temps, gmax, gsum, gcand, gcnt16, V, slen);
    k_finish<<<dim3(B), dim3(NTF), 0, stream>>>(
        logits, gcand, gcnt16, gmax, gsum, temps, minps, topps, topks, us, outp, V);
}

// Round 17
// 30.949 us; speedup vs baseline: 1.1372x; 1.0388x over previous
//
#include <hip/hip_runtime.h>
#include <hip/hip_bf16.h>
#include <stdint.h>

typedef unsigned long long u64;

#define S 16            // slices per row
#define SEGCAP 256      // per-slice candidate segment (expect ~182, 5.5-sigma safe)
#define NBF 8192        // fine bins for counting sort (range [2,8))
#define KBASE 0xC0000000u   // fkey(2.0f)
#define FSHIFT 11
#define KSHIFT 19       // coarse 13-bit key (slow path)
#define CAND_MAX 4096   // = S * SEGCAP
#define NT1 256
#define NW1 (NT1 / 64)
#define NTF 1024
#define NWF (NTF / 64)

__device__ __forceinline__ unsigned fkey(float x) {
    unsigned u = __float_as_uint(x);
    return ((int)u < 0) ? ~u : (u | 0x80000000u);
}

// ---------------- K1: single sweep: raw exp-sum + speculative collect ----------
// NO max computation (fast path needs none; slow path self-computes).
// 2-wide unrolled, dual sum chains, native exp (R14-proven config minus fmax).
__global__ __launch_bounds__(NT1) void k_pass1(
    const float* __restrict__ logits, const float* __restrict__ temps,
    float* __restrict__ gsum,
    u64* __restrict__ gcand, unsigned* __restrict__ gcnt16, int V, int slen)
{
    const int s = blockIdx.x, b = blockIdx.y, tid = threadIdx.x;
    __shared__ u64 buf[SEGCAP];
    __shared__ float reds[NW1];
    __shared__ unsigned s_cnt;
    if (tid == 0) s_cnt = 0u;
    __syncthreads();

    const float t = temps[b];
    const float invt = 1.0f / t;      // denom-only rounding class (accepted)
    const float* xrow = logits + (size_t)b * (size_t)V;
    const int beg = s * slen, end = min(V, beg + slen);
    const float4* x4 = (const float4*)xrow;
    const int beg4 = beg >> 2, end4 = end >> 2;

    float lsum0 = 0.f, lsum1 = 0.f;
    const float4 pad = make_float4(-INFINITY, -INFINITY, -INFINITY, -INFINITY);

    for (int idx = beg4 + tid; idx < end4; idx += 2 * NT1) {
        float4 a = x4[idx];
        const int jb = idx + NT1;
        float4 bv = (jb < end4) ? x4[jb] : pad;    // __expf(-inf)=0

        lsum0 += __expf(a.x * invt);  lsum0 += __expf(a.y * invt);
        lsum0 += __expf(a.z * invt);  lsum0 += __expf(a.w * invt);
        lsum1 += __expf(bv.x * invt); lsum1 += __expf(bv.y * invt);
        lsum1 += __expf(bv.z * invt); lsum1 += __expf(bv.w * invt);

        const int i0 = idx << 2;
        if (a.x >= 2.0f) { unsigned p = atomicAdd(&s_cnt, 1u); if (p < SEGCAP) buf[p] = ((u64)__float_as_uint(a.x) << 32) | (unsigned)(i0    ); }
        if (a.y >= 2.0f) { unsigned p = atomicAdd(&s_cnt, 1u); if (p < SEGCAP) buf[p] = ((u64)__float_as_uint(a.y) << 32) | (unsigned)(i0 + 1); }
        if (a.z >= 2.0f) { unsigned p = atomicAdd(&s_cnt, 1u); if (p < SEGCAP) buf[p] = ((u64)__float_as_uint(a.z) << 32) | (unsigned)(i0 + 2); }
        if (a.w >= 2.0f) { unsigned p = atomicAdd(&s_cnt, 1u); if (p < SEGCAP) buf[p] = ((u64)__float_as_uint(a.w) << 32) | (unsigned)(i0 + 3); }
        const int i1 = jb << 2;
        if (bv.x >= 2.0f) { unsigned p = atomicAdd(&s_cnt, 1u); if (p < SEGCAP) buf[p] = ((u64)__float_as_uint(bv.x) << 32) | (unsigned)(i1    ); }
        if (bv.y >= 2.0f) { unsigned p = atomicAdd(&s_cnt, 1u); if (p < SEGCAP) buf[p] = ((u64)__float_as_uint(bv.y) << 32) | (unsigned)(i1 + 1); }
        if (bv.z >= 2.0f) { unsigned p = atomicAdd(&s_cnt, 1u); if (p < SEGCAP) buf[p] = ((u64)__float_as_uint(bv.z) << 32) | (unsigned)(i1 + 2); }
        if (bv.w >= 2.0f) { unsigned p = atomicAdd(&s_cnt, 1u); if (p < SEGCAP) buf[p] = ((u64)__float_as_uint(bv.w) << 32) | (unsigned)(i1 + 3); }
    }
    for (int i = max(beg, end4 << 2) + tid; i < end; i += NT1) {
        float x = xrow[i];
        lsum0 += __expf(x * invt);
        if (x >= 2.0f) { unsigned p = atomicAdd(&s_cnt, 1u); if (p < SEGCAP) buf[p] = ((u64)__float_as_uint(x) << 32) | (unsigned)i; }
    }

    float lsum = lsum0 + lsum1;
    for (int off = 32; off > 0; off >>= 1) lsum += __shfl_xor(lsum, off);
    if ((tid & 63) == 0) reds[tid >> 6] = lsum;
    __syncthreads();
    if (tid == 0) {
        float sum = reds[0];
        for (int w = 1; w < NW1; ++w) sum += reds[w];
        gsum[b * S + s] = sum;            // raw sum of exp(x/t), no max shift
        gcnt16[b * S + s] = s_cnt;        // raw count (> SEGCAP -> slow path)
    }
    __syncthreads();
    const unsigned cw = min(s_cnt, (unsigned)SEGCAP);
    u64* dst = gcand + (size_t)b * CAND_MAX + (size_t)s * SEGCAP;
    for (int i = tid; i < SEGCAP; i += NT1)
        dst[i] = (i < (int)cw) ? buf[i] : 0ULL;   // sentinel-pad the tail
}

// ---------------- K2: per-row finish: counting sort (fast) / rescan+bitonic (slow) ----
__global__ __launch_bounds__(NTF) void k_finish(
    const float* __restrict__ logits, const u64* __restrict__ gcand,
    const unsigned* __restrict__ gcnt16, const float* __restrict__ gsum,
    const float* __restrict__ temps, const float* __restrict__ minps,
    const float* __restrict__ topps, const int* __restrict__ topks,
    const float* __restrict__ us, int* __restrict__ out, int V)
{
    const int b = blockIdx.x, tid = threadIdx.x;
    __shared__ u64 cand[CAND_MAX];
    __shared__ unsigned h[NBF + 1];
    __shared__ float wsum[NWF];
    __shared__ unsigned wfirst[NWF];
    __shared__ float s_m, s_den;
    __shared__ int s_thri;
    __shared__ unsigned s_cnt, s_n, s_tot;

    // T14 async-stage: issue candidate loads first (always safe: pass1 writes
    // every gcand word each call); latency hides under reductions + LDS zeroing.
    const u64* src = gcand + (size_t)b * CAND_MAX;
    u64 myc[CAND_MAX / NTF];
    #pragma unroll
    for (int k = 0; k < CAND_MAX / NTF; ++k)
        myc[k] = src[tid + k * NTF];

    const float t = temps[b];
    const int tk0 = topks[b];
    const unsigned tk0u = (unsigned)tk0;

    // wave 0: raw denom + total/overflow from slice partials
    if (tid < 64) {
        const int lane = tid;
        float d = (lane < S) ? gsum[b * S + lane] : 0.f;    // raw, no e^{-m}
        for (int off = 32; off > 0; off >>= 1) d += __shfl_xor(d, off);
        unsigned cs = (lane < S) ? gcnt16[b * S + lane] : 0u;
        unsigned ov = (cs > (unsigned)SEGCAP) ? 1u : 0u;
        unsigned tot = cs;
        for (int off = 32; off > 0; off >>= 1) { tot += __shfl_xor(tot, off); ov |= __shfl_xor(ov, off); }
        if (lane == 0) { s_den = d; s_tot = tot | (ov ? 0x80000000u : 0u); }
    }
    for (int i = tid; i <= NBF; i += NTF) h[i] = 0u;
    if (tid == 0) { s_cnt = 0u; s_thri = -1; }
    __syncthreads();
    const float denom = s_den;
    const unsigned totw = s_tot;
    const bool fast = !(totw & 0x80000000u) && totw >= tk0u
                      && isfinite(denom) && denom > 0.f;

    int n;
    if (fast) {
        // ---- fine histogram from preloaded registers (sentinel-skip) ----
        int mykf[CAND_MAX / NTF];
        #pragma unroll
        for (int k = 0; k < CAND_MAX / NTF; ++k) {
            mykf[k] = -1;
            if (myc[k] != 0ULL) {
                unsigned fk = ((unsigned)(myc[k] >> 32)) | 0x80000000u;  // fkey (x>0)
                unsigned kf = (fk - KBASE) >> FSHIFT;
                if (kf > (unsigned)(NBF - 1)) kf = NBF - 1;
                mykf[k] = (int)kf;
                atomicAdd(&h[kf], 1u);
            }
        }
        __syncthreads();

        // ---- block suffix-scan over h[0..NBF): h[bin] <- count above bin ----
        const int lane = tid & 63, wv = tid >> 6;
        unsigned cnt8[8];
        const int b0 = tid * 8;
        unsigned L = 0;
        #pragma unroll
        for (int j = 0; j < 8; ++j) { cnt8[j] = h[b0 + j]; L += cnt8[j]; }
        unsigned tsuf = L;
        #pragma unroll
        for (int off = 1; off < 64; off <<= 1) {
            unsigned o = __shfl_down(tsuf, off);
            if (lane + off < 64) tsuf += o;
        }
        if (lane == 0) wfirst[wv] = tsuf;
        __syncthreads();
        if (tid < 64) {
            unsigned sv = (tid < NWF) ? wfirst[tid] : 0u;
            #pragma unroll
            for (int off = 1; off < NWF; off <<= 1) {
                unsigned o = __shfl_down(sv, off);
                if (tid + off < NWF) sv += o;
            }
            if (tid < NWF) wfirst[tid] = sv;   // inclusive suffix of wave sums
        }
        __syncthreads();
        unsigned above = tsuf - L + ((wv + 1 < NWF) ? wfirst[wv + 1] : 0u);
        unsigned run = above;
        int mythr = -1;
        #pragma unroll
        for (int j = 7; j >= 0; --j) {
            unsigned incl = run + cnt8[j];
            if (mythr < 0 && incl >= tk0u) mythr = b0 + j;
            h[b0 + j] = run;
            run = incl;
        }
        __syncthreads();
        if (mythr >= 0) atomicMax(&s_thri, mythr);
        __syncthreads();
        const int thrbin = s_thri;
        if ((thrbin >> 3) == tid) s_n = h[thrbin] + cnt8[thrbin & 7];
        __syncthreads();
        n = (int)s_n;

        // ---- scatter: p = exp(x/t)/denom (raw, no shift), dest via per-bin atomic ----
        #pragma unroll
        for (int k = 0; k < CAND_MAX / NTF; ++k) {
            if (mykf[k] >= thrbin) {
                unsigned ub = (unsigned)(myc[k] >> 32);
                float x = __uint_as_float(ub);
                float p = expf(x / t) / denom;
                unsigned dest = atomicAdd(&h[mykf[k]], 1u);
                if (dest < (unsigned)CAND_MAX)
                    cand[dest] = ((u64)__float_as_uint(p) << 32) | (unsigned)(~(unsigned)myc[k]);
            }
        }
        __syncthreads();

        // ---- fixup: insertion-sort multi-element bins (desc by composite) ----
        for (int bb = thrbin + tid; bb < NBF; bb += NTF) {
            unsigned endo = h[bb];          // post-scatter = start + cnt
            unsigned starto = h[bb + 1];    // = start of bin bb
            if (endo > starto + 1 && starto < tk0u) {
                for (unsigned ii = starto + 1; ii < endo; ++ii) {
                    u64 key = cand[ii];
                    unsigned jj = ii;
                    while (jj > starto && cand[jj - 1] < key) { cand[jj] = cand[jj - 1]; --jj; }
                    cand[jj] = key;
                }
            }
        }
        __syncthreads();
    } else {
        // ---- slow path (adversarial only): row max, hist + denom, rescan, bitonic ----
        const int lane = tid & 63, wv = tid >> 6;
        const float* xrow = logits + (size_t)b * (size_t)V;
        const float4* x4 = (const float4*)xrow;
        const int n4 = V >> 2;

        // row max (pass1 no longer provides it)
        float lmx = -INFINITY;
        for (int i = tid; i < n4; i += NTF) {
            float4 v = x4[i];
            lmx = fmaxf(lmx, fmaxf(fmaxf(v.x, v.y), fmaxf(v.z, v.w)));
        }
        for (int i = (n4 << 2) + tid; i < V; i += NTF) lmx = fmaxf(lmx, xrow[i]);
        for (int off = 32; off > 0; off >>= 1) lmx = fmaxf(lmx, __shfl_xor(lmx, off));
        if (lane == 0) wsum[wv] = lmx;
        __syncthreads();
        if (tid == 0) {
            float r = wsum[0];
            for (int w = 1; w < NWF; ++w) r = fmaxf(r, wsum[w]);
            s_m = r / t;
        }
        __syncthreads();
        const float m2 = s_m;

        float lsum = 0.f;
        for (int i = tid; i < n4; i += NTF) {
            float4 v = x4[i];
            lsum += expf(v.x / t - m2); lsum += expf(v.y / t - m2);
            lsum += expf(v.z / t - m2); lsum += expf(v.w / t - m2);
            atomicAdd(&h[fkey(v.x) >> KSHIFT], 1u);
            atomicAdd(&h[fkey(v.y) >> KSHIFT], 1u);
            atomicAdd(&h[fkey(v.z) >> KSHIFT], 1u);
            atomicAdd(&h[fkey(v.w) >> KSHIFT], 1u);
        }
        for (int i = (n4 << 2) + tid; i < V; i += NTF) {
            lsum += expf(xrow[i] / t - m2);
            atomicAdd(&h[fkey(xrow[i]) >> KSHIFT], 1u);
        }
        for (int off = 32; off > 0; off >>= 1) lsum += __shfl_xor(lsum, off);
        if (lane == 0) wsum[wv] = lsum;
        __syncthreads();
        if (tid == 0) {
            float d = 0.f;
            for (int w = 0; w < NWF; ++w) d += wsum[w];
            s_den = d;
        }
        __syncthreads();
        const float den2 = s_den;
        if (tid < 64) {
            const unsigned needed = tk0u;
            const int CH = NBF / 64;
            const int base = tid * CH;
            unsigned c = 0;
            for (int j = 0; j < CH; ++j) c += h[base + j];
            unsigned tsuf = c;
            for (int off = 1; off < 64; off <<= 1) {
                unsigned o = __shfl_down(tsuf, off);
                if (tid + off < 64) tsuf += o;
            }
            u64 mask = __ballot(tsuf >= needed);
            int lstar = 63 - __builtin_clzll(mask);
            unsigned above = __shfl(tsuf, (lstar + 1) & 63);
            if (lstar == 63) above = 0u;
            if (tid == 0) {
                unsigned run = above;
                int thrb = lstar * CH;
                for (int bb2 = lstar * CH + CH - 1; bb2 >= lstar * CH; --bb2) {
                    run += h[bb2];
                    if (run >= needed) { thrb = bb2; break; }
                }
                s_thri = thrb;
            }
        }
        __syncthreads();
        const unsigned thr = (unsigned)s_thri << KSHIFT;
        for (int i = tid; i < n4; i += NTF) {
            float4 v = x4[i];
            const int i0 = i << 2;
            #pragma unroll
            for (int c = 0; c < 4; ++c) {
                float x = (c == 0) ? v.x : (c == 1) ? v.y : (c == 2) ? v.z : v.w;
                if (fkey(x) >= thr) {
                    float p = expf(x / t - m2) / den2;
                    unsigned pos = atomicAdd(&s_cnt, 1u);
                    if (pos < CAND_MAX)
                        cand[pos] = ((u64)__float_as_uint(p) << 32) | (unsigned)(~(unsigned)(i0 + c));
                }
            }
        }
        for (int i = (n4 << 2) + tid; i < V; i += NTF) {
            float x = xrow[i];
            if (fkey(x) >= thr) {
                float p = expf(x / t - m2) / den2;
                unsigned pos = atomicAdd(&s_cnt, 1u);
                if (pos < CAND_MAX)
                    cand[pos] = ((u64)__float_as_uint(p) << 32) | (unsigned)(~(unsigned)i);
            }
        }
        __syncthreads();
        n = (int)min(s_cnt, (unsigned)CAND_MAX);
        int n2 = 1; while (n2 < n) n2 <<= 1;
        for (int i = n + tid; i < n2; i += NTF) cand[i] = 0ULL;
        __syncthreads();
        for (int k = 2; k <= n2; k <<= 1) {
            for (int j = k >> 1; j > 0; j >>= 1) {
                for (int i = tid; i < n2; i += NTF) {
                    int ixj = i ^ j;
                    if (ixj > i) {
                        u64 a = cand[i], bb2 = cand[ixj];
                        bool sw = ((i & k) == 0) ? (a < bb2) : (a > bb2);
                        if (sw) { cand[i] = bb2; cand[ixj] = a; }
                    }
                }
                __syncthreads();
            }
        }
    }

    // ---- parallel epilogue: thread i owns sorted element i ----
    const int lane = tid & 63, wv = tid >> 6;
    const float topp = topps[b], minp = minps[b], uu = us[b];
    int tk = tk0;
    if (tk > n) tk = n;
    if (tk > NTF) tk = NTF;

    float p = 0.f;
    if (tid < tk) p = __uint_as_float((unsigned)(cand[tid] >> 32));

    float c = p;
    #pragma unroll
    for (int off = 1; off < 64; off <<= 1) {
        float o = __shfl_up(c, off);
        if (lane >= off) c += o;
    }
    if (lane == 63) wsum[wv] = c;
    __syncthreads();
    if (tid < 64) {
        float sv = (tid < NWF) ? wsum[tid] : 0.f;
        #pragma unroll
        for (int off = 1; off < NWF; off <<= 1) {
            float o = __shfl_up(sv, off);
            if (tid >= off) sv += o;
        }
        if (tid < NWF) wsum[tid] = sv;
    }
    __syncthreads();
    float cum = c + ((wv > 0) ? wsum[wv - 1] : 0.f);
    float excl = cum - p;                       // replicate (cumsum - p) rounding shape
    float p0 = __uint_as_float((unsigned)(cand[0] >> 32));
    float thrmp = p0 * minp;
    float p1v = (excl <= topp) ? p : 0.f;
    float v = (p1v >= thrmp) ? p1v : 0.f;
    __syncthreads();

    float cv = v;
    #pragma unroll
    for (int off = 1; off < 64; off <<= 1) {
        float o = __shfl_up(cv, off);
        if (lane >= off) cv += o;
    }
    if (lane == 63) wsum[wv] = cv;
    __syncthreads();
    if (tid < 64) {
        float sv = (tid < NWF) ? wsum[tid] : 0.f;
        #pragma unroll
        for (int off = 1; off < NWF; off <<= 1) {
            float o = __shfl_up(sv, off);
            if (tid >= off) sv += o;
        }
        if (tid < NWF) wsum[tid] = sv;
    }
    __syncthreads();
    float cdf = cv + ((wv > 0) ? wsum[wv - 1] : 0.f);
    float total = wsum[NWF - 1];
    float target = uu * total;

    bool hit = (tid < tk) && (cdf > target);
    u64 mk = __ballot(hit);
    if (lane == 0) wfirst[wv] = mk ? (unsigned)__builtin_ctzll(mk) : 0xFFFFFFFFu;
    __syncthreads();
    if (tid == 0) {
        int sel = -1;
        for (int w = 0; w < NWF; ++w)
            if (wfirst[w] != 0xFFFFFFFFu) { sel = w * 64 + (int)wfirst[w]; break; }
        if (sel < 0) sel = 0;
        out[b] = (int)~(unsigned)cand[sel];
    }
}

// ---------------- Fallback: monolithic single kernel (round-1, passed) ----------------
#define FNT 512
#define FNBINS 1024
#define FKMARGIN 1224
__global__ __launch_bounds__(FNT) void sampler_mono(
    const float* __restrict__ logits, const float* __restrict__ temps,
    const float* __restrict__ minps, const float* __restrict__ topps,
    const int* __restrict__ topks, const float* __restrict__ us,
    int* __restrict__ out, int V)
{
    const int row = blockIdx.x;
    const int tid = threadIdx.x;
    const float t = temps[row];
    __shared__ unsigned int hist[FNBINS];
    __shared__ u64 cand[CAND_MAX];
    __shared__ float red[FNT / 64];
    __shared__ float s_m, s_denom;
    __shared__ unsigned s_thr, s_cnt;
    for (int i = tid; i < FNBINS; i += FNT) hist[i] = 0u;
    if (tid == 0) s_cnt = 0u;
    const float* xrow = logits + (size_t)row * (size_t)V;
    const int n4 = V >> 2;
    const float4* x4 = (const float4*)xrow;
    float lmax = -INFINITY;
    for (int i = tid; i < n4; i += FNT) {
        float4 v = x4[i];
        lmax = fmaxf(lmax, fmaxf(fmaxf(v.x, v.y), fmaxf(v.z, v.w)));
    }
    for (int i = (n4 << 2) + tid; i < V; i += FNT) lmax = fmaxf(lmax, xrow[i]);
    for (int off = 32; off > 0; off >>= 1) lmax = fmaxf(lmax, __shfl_xor(lmax, off));
    if ((tid & 63) == 0) red[tid >> 6] = lmax;
    __syncthreads();
    if (tid == 0) {
        float r = red[0];
        for (int w = 1; w < FNT / 64; ++w) r = fmaxf(r, red[w]);
        s_m = r / t;
    }
    __syncthreads();
    const float m = s_m;
    float lsum = 0.f;
    for (int i = tid; i < n4; i += FNT) {
        float4 v = x4[i];
        float e0 = expf(v.x / t - m), e1 = expf(v.y / t - m);
        float e2 = expf(v.z / t - m), e3 = expf(v.w / t - m);
        lsum += e0; lsum += e1; lsum += e2; lsum += e3;
        atomicAdd(&hist[__float_as_uint(e0) >> 20], 1u);
        atomicAdd(&hist[__float_as_uint(e1) >> 20], 1u);
        atomicAdd(&hist[__float_as_uint(e2) >> 20], 1u);
        atomicAdd(&hist[__float_as_uint(e3) >> 20], 1u);
    }
    for (int i = (n4 << 2) + tid; i < V; i += FNT) {
        float e = expf(xrow[i] / t - m);
        lsum += e;
        atomicAdd(&hist[__float_as_uint(e) >> 20], 1u);
    }
    for (int off = 32; off > 0; off >>= 1) lsum += __shfl_xor(lsum, off);
    if ((tid & 63) == 0) red[tid >> 6] = lsum;
    __syncthreads();
    if (tid == 0) {
        float r = 0.f;
        for (int w = 0; w < FNT / 64; ++w) r += red[w];
        s_denom = r;
    }
    __syncthreads();
    const float denom = s_denom;
    if (tid < 64) {
        const int lane = tid;
        const int CH = FNBINS / 64;
        const int base = lane * CH;
        unsigned c = 0;
        #pragma unroll
        for (int j = 0; j < CH; ++j) c += hist[base + j];
        unsigned tsuf = c;
        #pragma unroll
        for (int off = 1; off < 64; off <<= 1) {
            unsigned o = __shfl_down(tsuf, off);
            if (lane + off < 64) tsuf += o;
        }
        unsigned long long mask = __ballot(tsuf >= (unsigned)FKMARGIN);
        int lstar = 63 - __builtin_clzll(mask);
        unsigned above = __shfl(tsuf, (lstar + 1) & 63);
        if (lstar == 63) above = 0u;
        if (lane == 0) {
            unsigned run = above;
            int thrbin = lstar * CH;
            for (int bb = lstar * CH + CH - 1; bb >= lstar * CH; --bb) {
                run += hist[bb];
                if (run >= (unsigned)FKMARGIN) { thrbin = bb; break; }
            }
            s_thr = (unsigned)thrbin << 20;
        }
    }
    __syncthreads();
    const unsigned thrkey = s_thr;
    for (int i = tid; i < n4; i += FNT) {
        float4 v = x4[i];
        float e[4] = { expf(v.x / t - m), expf(v.y / t - m),
                       expf(v.z / t - m), expf(v.w / t - m) };
        #pragma unroll
        for (int c = 0; c < 4; ++c) {
            unsigned eb = __float_as_uint(e[c]);
            if (eb >= thrkey) {
                float p = e[c] / denom;
                unsigned pos = atomicAdd(&s_cnt, 1u);
                if (pos < CAND_MAX)
                    cand[pos] = ((u64)__float_as_uint(p) << 32) | (unsigned)(~(unsigned)((i << 2) + c));
            }
        }
    }
    for (int i = (n4 << 2) + tid; i < V; i += FNT) {
        float e = expf(xrow[i] / t - m);
        if (__float_as_uint(e) >= thrkey) {
            float p = e / denom;
            unsigned pos = atomicAdd(&s_cnt, 1u);
            if (pos < CAND_MAX)
                cand[pos] = ((u64)__float_as_uint(p) << 32) | (unsigned)(~(unsigned)i);
        }
    }
    __syncthreads();
    int n = (int)s_cnt; if (n > CAND_MAX) n = CAND_MAX;
    int n2 = 1; while (n2 < n) n2 <<= 1;
    for (int i = n + tid; i < n2; i += FNT) cand[i] = 0ULL;
    __syncthreads();
    for (int k = 2; k <= n2; k <<= 1) {
        for (int j = k >> 1; j > 0; j >>= 1) {
            for (int i = tid; i < n2; i += FNT) {
                int ixj = i ^ j;
                if (ixj > i) {
                    u64 a = cand[i], bb = cand[ixj];
                    bool sw = ((i & k) == 0) ? (a < bb) : (a > bb);
                    if (sw) { cand[i] = bb; cand[ixj] = a; }
                }
            }
            __syncthreads();
        }
    }
    if (tid == 0) {
        const float topp = topps[row], minp = minps[row], uu = us[row];
        int tk = topks[row];
        if (tk > n) tk = n;
        float p0 = __uint_as_float((unsigned)(cand[0] >> 32));
        float thrmp = p0 * minp;
        float cum = 0.f, total = 0.f;
        for (int i = 0; i < tk; ++i) {
            float p = __uint_as_float((unsigned)(cand[i] >> 32));
            cum = cum + p;
            float excl = cum - p;
            float p1 = (excl <= topp) ? p : 0.f;
            float v = (p1 >= thrmp) ? p1 : 0.f;
            total += v;
        }
        float target = uu * total;
        float cdf = 0.f; int sel = -1;
        cum = 0.f;
        for (int i = 0; i < tk; ++i) {
            float p = __uint_as_float((unsigned)(cand[i] >> 32));
            cum = cum + p;
            float excl = cum - p;
            float p1 = (excl <= topp) ? p : 0.f;
            float v = (p1 >= thrmp) ? p1 : 0.f;
            cdf += v;
            if (cdf > target) { sel = i; break; }
        }
        if (sel < 0) sel = 0;
        out[row] = (int)~(unsigned)cand[sel];
    }
}

extern "C" void kernel_launch(void* const* d_in, const int* in_sizes, int n_in,
                              void* d_out, int out_size, void* d_ws, size_t ws_size,
                              hipStream_t stream) {
    const float* logits = (const float*)d_in[0];
    const float* temps  = (const float*)d_in[1];
    const float* minps  = (const float*)d_in[2];
    const float* topps  = (const float*)d_in[3];
    const int*   topks  = (const int*)d_in[4];
    const float* us     = (const float*)d_in[5];
    const int B = in_sizes[1];
    const int V = in_sizes[0] / B;
    int* outp = (int*)d_out;

    const int slen = (((V + S - 1) / S) + 3) & ~3;   // slice length, mult of 4

    size_t need = 0;
    const size_t off_cand = need; need += (size_t)B * CAND_MAX * sizeof(u64);
    const size_t off_cnt  = need; need += (size_t)B * S * sizeof(unsigned);
    const size_t off_sum  = need; need += (size_t)B * S * sizeof(float);

    if (ws_size < need) {
        sampler_mono<<<dim3(B), dim3(FNT), 0, stream>>>(
            logits, temps, minps, topps, topks, us, outp, V);
        return;
    }

    char* w = (char*)d_ws;
    u64*      gcand  = (u64*)(w + off_cand);
    unsigned* gcnt16 = (unsigned*)(w + off_cnt);
    float*    gsum   = (float*)(w + off_sum);

    // No workspace zeroing needed: every word read is written this call.
    k_pass1<<<dim3(S, B), dim3(NT1), 0, stream>>>(
        logits, temps, gsum, gcand, gcnt16, V, slen);
    k_finish<<<dim3(B), dim3(NTF), 0, stream>>>(
        logits, gcand, gcnt16, gsum, temps, minps, topps, topks, us, outp, V);
}